// Round 1
// baseline (1091.783 us; speedup 1.0000x reference)
//
#include <hip/hip_runtime.h>
#include <cstdint>
#include <cstddef>

#define EPS 1e-6f
#define RPB 16

// ---------------------------------------------------------------------------
// Kernel S: per-batch mask scan -> compacted valid list + counts.
// Detects mask storage (int32 words vs raw bool bytes) at runtime: batch 0 is
// all-True, so byte layout gives words 0x01010101 > 1; int32 layout is 0/1.
// ---------------------------------------------------------------------------
__global__ __launch_bounds__(256) void k_scan(const void* __restrict__ maskp,
                                              int* __restrict__ v_list,
                                              int* __restrict__ counts) {
    __shared__ int sc[256];
    __shared__ int mode_s;
    const int tid = threadIdx.x;
    const int b = blockIdx.x;
    const uint32_t* mi = (const uint32_t*)maskp;
    const uint8_t* mb = (const uint8_t*)maskp;

    if (tid == 0) mode_s = 0;
    __syncthreads();
    int bad = 0;
    for (int k = tid; k < 1024; k += 256) bad |= (mi[k] > 1u) ? 1 : 0;
    if (bad) mode_s = 1;  // racy same-value write is fine
    __syncthreads();
    const int byte_mode = mode_s;

    int base = 0;
    for (int chunk = 0; chunk < 16; ++chunk) {
        const int i = chunk * 256 + tid;
        int m;
        if (byte_mode) m = mb[(b << 12) + i] ? 1 : 0;
        else           m = mi[(b << 12) + i] ? 1 : 0;
        sc[tid] = m;
        __syncthreads();
        for (int off = 1; off < 256; off <<= 1) {
            int v = sc[tid];
            int a = (tid >= off) ? sc[tid - off] : 0;
            __syncthreads();
            sc[tid] = v + a;
            __syncthreads();
        }
        const int incl = sc[tid];
        const int tot = sc[255];
        if (m) v_list[(b << 12) + base + incl - 1] = i;
        base += tot;
        __syncthreads();  // protect sc before next chunk overwrites
    }
    if (tid == 0) counts[b] = base;
}

// ---------------------------------------------------------------------------
// Kernel A12: rmsnorm(token_embeds, w_pre) fused with feats_pre = tok @ W_down^T
// 8 tokens per block staged in LDS; each thread computes 2 output cols x 8 rows.
// ---------------------------------------------------------------------------
__global__ __launch_bounds__(256) void k_token_feats(
    const float* __restrict__ tokens,   // [4096,1024]
    const float* __restrict__ w_pre,    // [1024]
    const float* __restrict__ W_down,   // [512,1024]
    float* __restrict__ feats_pre)      // [4096,512]
{
    __shared__ float tok_s[8][1024];
    __shared__ float red[4][8];
    __shared__ float rms_s[8];
    const int tid = threadIdx.x;
    const int lane = tid & 63, wave = tid >> 6;
    const int row0 = blockIdx.x * 8;

    float4 xv[8];
    float ss[8];
#pragma unroll
    for (int g = 0; g < 8; ++g) {
        xv[g] = *(const float4*)&tokens[(size_t)(row0 + g) * 1024 + 4 * tid];
        ss[g] = xv[g].x * xv[g].x + xv[g].y * xv[g].y + xv[g].z * xv[g].z + xv[g].w * xv[g].w;
    }
#pragma unroll
    for (int g = 0; g < 8; ++g) {
#pragma unroll
        for (int off = 32; off > 0; off >>= 1) ss[g] += __shfl_down(ss[g], off);
    }
    if (lane == 0) {
#pragma unroll
        for (int g = 0; g < 8; ++g) red[wave][g] = ss[g];
    }
    __syncthreads();
    if (tid < 8) {
        float s = red[0][tid] + red[1][tid] + red[2][tid] + red[3][tid];
        rms_s[tid] = rsqrtf(s * (1.0f / 1024.0f) + EPS);
    }
    __syncthreads();
    const float4 wp = *(const float4*)&w_pre[4 * tid];
#pragma unroll
    for (int g = 0; g < 8; ++g) {
        const float r = rms_s[g];
        tok_s[g][4 * tid + 0] = xv[g].x * wp.x * r;
        tok_s[g][4 * tid + 1] = xv[g].y * wp.y * r;
        tok_s[g][4 * tid + 2] = xv[g].z * wp.z * r;
        tok_s[g][4 * tid + 3] = xv[g].w * wp.w * r;
    }
    __syncthreads();

    const int e0 = tid * 2;
    const float* Wd0 = W_down + (size_t)e0 * 1024;
    const float* Wd1 = Wd0 + 1024;
    float acc0[8], acc1[8];
#pragma unroll
    for (int g = 0; g < 8; ++g) { acc0[g] = 0.f; acc1[g] = 0.f; }
    for (int k = 0; k < 1024; k += 4) {
        const float4 w0 = *(const float4*)&Wd0[k];
        const float4 w1 = *(const float4*)&Wd1[k];
#pragma unroll
        for (int g = 0; g < 8; ++g) {
            const float4 t = *(const float4*)&tok_s[g][k];
            acc0[g] += t.x * w0.x + t.y * w0.y + t.z * w0.z + t.w * w0.w;
            acc1[g] += t.x * w1.x + t.y * w1.y + t.z * w1.z + t.w * w1.w;
        }
    }
#pragma unroll
    for (int g = 0; g < 8; ++g) {
        float2 o; o.x = acc0[g]; o.y = acc1[g];
        *(float2*)&feats_pre[(size_t)(row0 + g) * 512 + e0] = o;
    }
}

// ---------------------------------------------------------------------------
// Kernel A3: one wave per token: rmsnorm(feats_pre, w_tok) -> silu -> W_proj
// outputs (1+scale, shift, sigmoid(gate)) into params[token][4].
// ---------------------------------------------------------------------------
__global__ __launch_bounds__(64) void k_params(
    const float* __restrict__ feats_pre, // [4096,512]
    const float* __restrict__ w_tok,     // [512]
    const float* __restrict__ W_proj,    // [3,512]
    float* __restrict__ params)          // [4096,4]
{
    const int tk = blockIdx.x;
    const int lane = threadIdx.x;
    const int d0 = lane * 8;
    const float* fp = feats_pre + (size_t)tk * 512 + d0;
    const float4 f0 = *(const float4*)&fp[0];
    const float4 f1 = *(const float4*)&fp[4];
    float ss = f0.x * f0.x + f0.y * f0.y + f0.z * f0.z + f0.w * f0.w
             + f1.x * f1.x + f1.y * f1.y + f1.z * f1.z + f1.w * f1.w;
#pragma unroll
    for (int off = 32; off > 0; off >>= 1) ss += __shfl_down(ss, off);
    ss = __shfl(ss, 0);
    const float rms = rsqrtf(ss * (1.0f / 512.0f) + EPS);

    const float4 wt0 = *(const float4*)&w_tok[d0];
    const float4 wt1 = *(const float4*)&w_tok[d0 + 4];
    float fv[8] = {f0.x, f0.y, f0.z, f0.w, f1.x, f1.y, f1.z, f1.w};
    float wv[8] = {wt0.x, wt0.y, wt0.z, wt0.w, wt1.x, wt1.y, wt1.z, wt1.w};
    float s[8];
#pragma unroll
    for (int j = 0; j < 8; ++j) {
        const float v = fv[j] * wv[j] * rms;
        s[j] = v / (1.0f + expf(-v));
    }
    float p[3];
#pragma unroll
    for (int q = 0; q < 3; ++q) {
        const float* Wp = W_proj + (size_t)q * 512 + d0;
        const float4 a = *(const float4*)&Wp[0];
        const float4 c = *(const float4*)&Wp[4];
        p[q] = s[0] * a.x + s[1] * a.y + s[2] * a.z + s[3] * a.w
             + s[4] * c.x + s[5] * c.y + s[6] * c.z + s[7] * c.w;
#pragma unroll
        for (int off = 32; off > 0; off >>= 1) p[q] += __shfl_down(p[q], off);
    }
    if (lane == 0) {
        float* po = params + (size_t)tk * 4;
        po[0] = 1.0f + p[0];
        po[1] = p[1];
        po[2] = 1.0f / (1.0f + expf(-p[2]));
    }
}

// ---------------------------------------------------------------------------
// Kernel F: fill output rows j >= counts[b] with filler_embed.
// One float4 per thread.
// ---------------------------------------------------------------------------
__global__ __launch_bounds__(256) void k_fill(
    const float* __restrict__ filler,   // [512]
    const int* __restrict__ counts,     // [16]
    float* __restrict__ out)            // [16,4096,512]
{
    const int gid = blockIdx.x * 256 + threadIdx.x;
    const size_t e4 = (size_t)gid * 4;
    const int slot = gid >> 7;          // 128 float4 per 512-row
    const int b = slot >> 12;
    const int j = slot & 4095;
    if (j >= counts[b]) {
        const int e0 = (int)(e4 & 511);
        *(float4*)&out[e4] = *(const float4*)&filler[e0];
    }
}

// ---------------------------------------------------------------------------
// Kernel B: fusion GEMM over compacted valid rows. 16 rows/block.
// Phase 1: rmsnorm(char row) -> h = silu(cn*(1+scale)+shift) staged in LDS.
// Phase 2: fp32 register-tiled GEMM vs W_fusion (2 cols x 16 rows / thread).
// Epilogue: out = gate*fused + (1-gate)*cn (cn recomputed from reloaded x).
// ---------------------------------------------------------------------------
__global__ __launch_bounds__(256) void k_fusion(
    const float* __restrict__ chars,    // [16*4096,512]
    const float* __restrict__ w_char,   // [512]
    const float* __restrict__ W_fus,    // [512,512]
    const float* __restrict__ params,   // [4096,4]
    const int* __restrict__ v_list,     // [16,4096]
    const int* __restrict__ counts,     // [16]
    float* __restrict__ out)            // [16,4096,512]
{
    __shared__ float h_s[RPB][512];
    __shared__ float red[4][RPB];
    __shared__ float rms_s[RPB];
    __shared__ int iv_s[RPB];
    __shared__ float s1_s[RPB], sh_s[RPB], gt_s[RPB];

    const int tid = threadIdx.x;
    const int lane = tid & 63, wave = tid >> 6;
    const int b = blockIdx.x >> 8;
    const int jb = (blockIdx.x & 255) * RPB;
    const int cnt = counts[b];
    if (jb >= cnt) return;
    const int nr = min(RPB, cnt - jb);

    if (tid < RPB) {
        const int j = jb + tid;
        const int i = (j < cnt) ? v_list[(b << 12) + j] : v_list[b << 12];
        iv_s[tid] = i;
        const float* pp = params + (size_t)((b << 8) + (i >> 4)) * 4;
        s1_s[tid] = pp[0];
        sh_s[tid] = pp[1];
        gt_s[tid] = pp[2];
    }
    __syncthreads();

    const int d0 = tid * 2;
    const float2 wc = *(const float2*)&w_char[d0];

    float2 xv[RPB];
    float ss[RPB];
#pragma unroll
    for (int r = 0; r < RPB; ++r) {
        const float* xp = chars + ((size_t)(b << 12) + iv_s[r]) * 512;
        xv[r] = *(const float2*)&xp[d0];
        ss[r] = xv[r].x * xv[r].x + xv[r].y * xv[r].y;
    }
#pragma unroll
    for (int r = 0; r < RPB; ++r) {
#pragma unroll
        for (int off = 32; off > 0; off >>= 1) ss[r] += __shfl_down(ss[r], off);
    }
    if (lane == 0) {
#pragma unroll
        for (int r = 0; r < RPB; ++r) red[wave][r] = ss[r];
    }
    __syncthreads();
    if (tid < RPB) {
        const float s = red[0][tid] + red[1][tid] + red[2][tid] + red[3][tid];
        rms_s[tid] = rsqrtf(s * (1.0f / 512.0f) + EPS);
    }
    __syncthreads();
#pragma unroll
    for (int r = 0; r < RPB; ++r) {
        const float rm = rms_s[r], s1 = s1_s[r], sh = sh_s[r];
        const float c0 = wc.x * xv[r].x * rm;
        const float c1 = wc.y * xv[r].y * rm;
        const float a0 = c0 * s1 + sh;
        const float a1 = c1 * s1 + sh;
        h_s[r][d0]     = a0 / (1.0f + expf(-a0));
        h_s[r][d0 + 1] = a1 / (1.0f + expf(-a1));
    }
    if (nr < RPB) {
        for (int r = nr; r < RPB; ++r) { h_s[r][d0] = 0.f; h_s[r][d0 + 1] = 0.f; }
    }
    __syncthreads();

    // GEMM: fused[r][e] = sum_d h[r][d] * W_fus[e][d]
    const int e0 = tid * 2;
    const float* W0 = W_fus + (size_t)e0 * 512;
    const float* W1 = W0 + 512;
    float acc0[RPB], acc1[RPB];
#pragma unroll
    for (int r = 0; r < RPB; ++r) { acc0[r] = 0.f; acc1[r] = 0.f; }
    for (int d = 0; d < 512; d += 4) {
        const float4 w0 = *(const float4*)&W0[d];
        const float4 w1 = *(const float4*)&W1[d];
#pragma unroll
        for (int r = 0; r < RPB; ++r) {
            const float4 h = *(const float4*)&h_s[r][d];
            acc0[r] += h.x * w0.x + h.y * w0.y + h.z * w0.z + h.w * w0.w;
            acc1[r] += h.x * w1.x + h.y * w1.y + h.z * w1.z + h.w * w1.w;
        }
    }

    // Epilogue
    for (int r = 0; r < nr; ++r) {
        const float* xp = chars + ((size_t)(b << 12) + iv_s[r]) * 512;
        const float2 x2 = *(const float2*)&xp[e0];
        const float rm = rms_s[r], g = gt_s[r];
        const float c0 = wc.x * x2.x * rm;
        const float c1 = wc.y * x2.y * rm;
        float2 o;
        o.x = g * acc0[r] + (1.0f - g) * c0;
        o.y = g * acc1[r] + (1.0f - g) * c1;
        *(float2*)&out[((size_t)(b << 12) + jb + r) * 512 + e0] = o;
    }
}

// ---------------------------------------------------------------------------
extern "C" void kernel_launch(void* const* d_in, const int* in_sizes, int n_in,
                              void* d_out, int out_size, void* d_ws, size_t ws_size,
                              hipStream_t stream) {
    const float* tokens = (const float*)d_in[0];
    // d_in[1] token_ids_mask: unused by the reference
    const float* chars  = (const float*)d_in[2];
    const void*  cmask  = d_in[3];
    const float* filler = (const float*)d_in[4];
    const float* w_pre  = (const float*)d_in[5];
    const float* w_tok  = (const float*)d_in[6];
    const float* w_char = (const float*)d_in[7];
    const float* W_down = (const float*)d_in[8];
    const float* W_proj = (const float*)d_in[9];
    const float* W_fus  = (const float*)d_in[10];
    float* out = (float*)d_out;

    float* feats_pre = (float*)d_ws;                        // 4096*512 f32
    float* params    = feats_pre + (size_t)4096 * 512;      // 4096*4 f32
    int*   counts    = (int*)(params + (size_t)4096 * 4);   // 16 int
    int*   v_list    = counts + 16;                         // 16*4096 int

    k_scan<<<16, 256, 0, stream>>>(cmask, v_list, counts);
    k_token_feats<<<512, 256, 0, stream>>>(tokens, w_pre, W_down, feats_pre);
    k_params<<<4096, 64, 0, stream>>>(feats_pre, w_tok, W_proj, params);
    k_fill<<<32768, 256, 0, stream>>>(filler, counts, out);
    k_fusion<<<4096, 256, 0, stream>>>(chars, w_char, W_fus, params, v_list, counts, out);
}

// Round 2
// 369.967 us; speedup vs baseline: 2.9510x; 2.9510x over previous
//
#include <hip/hip_runtime.h>
#include <cstdint>
#include <cstddef>

#define EPS 1e-6f

typedef short bf16x8 __attribute__((ext_vector_type(8)));
typedef float f32x4  __attribute__((ext_vector_type(4)));

__device__ __forceinline__ short f2bf(float x) {
    uint32_t u = __builtin_bit_cast(uint32_t, x);
    return (short)((u + 0x7FFFu + ((u >> 16) & 1u)) >> 16);
}

// ---------------------------------------------------------------------------
// Kernel S: per-batch mask scan -> compacted valid list + counts.
// ---------------------------------------------------------------------------
__global__ __launch_bounds__(256) void k_scan(const void* __restrict__ maskp,
                                              int* __restrict__ v_list,
                                              int* __restrict__ counts) {
    __shared__ int sc[256];
    __shared__ int mode_s;
    const int tid = threadIdx.x;
    const int b = blockIdx.x;
    const uint32_t* mi = (const uint32_t*)maskp;
    const uint8_t* mb = (const uint8_t*)maskp;

    if (tid == 0) mode_s = 0;
    __syncthreads();
    int bad = 0;
    for (int k = tid; k < 1024; k += 256) bad |= (mi[k] > 1u) ? 1 : 0;
    if (bad) mode_s = 1;
    __syncthreads();
    const int byte_mode = mode_s;

    int base = 0;
    for (int chunk = 0; chunk < 16; ++chunk) {
        const int i = chunk * 256 + tid;
        int m;
        if (byte_mode) m = mb[(b << 12) + i] ? 1 : 0;
        else           m = mi[(b << 12) + i] ? 1 : 0;
        sc[tid] = m;
        __syncthreads();
        for (int off = 1; off < 256; off <<= 1) {
            int v = sc[tid];
            int a = (tid >= off) ? sc[tid - off] : 0;
            __syncthreads();
            sc[tid] = v + a;
            __syncthreads();
        }
        const int incl = sc[tid];
        const int tot = sc[255];
        if (m) v_list[(b << 12) + base + incl - 1] = i;
        base += tot;
        __syncthreads();
    }
    if (tid == 0) counts[b] = base;
}

// ---------------------------------------------------------------------------
// Kernel conv: fp32 -> bf16 (RNE), n4 float4 groups.
// ---------------------------------------------------------------------------
__global__ __launch_bounds__(256) void k_conv(const float* __restrict__ src,
                                              short* __restrict__ dst, int n4) {
    const int gid = blockIdx.x * 256 + threadIdx.x;
    if (gid >= n4) return;
    const float4 v = ((const float4*)src)[gid];
    short4 o;
    o.x = f2bf(v.x); o.y = f2bf(v.y); o.z = f2bf(v.z); o.w = f2bf(v.w);
    ((short4*)dst)[gid] = o;
}

// ---------------------------------------------------------------------------
// Kernel TP: token rmsnorm -> bf16 rows. One wave per row (1024 elems).
// ---------------------------------------------------------------------------
__global__ __launch_bounds__(256) void k_tokprep(const float* __restrict__ tokens,
                                                 const float* __restrict__ w_pre,
                                                 short* __restrict__ tokbf) {
    const int tid = threadIdx.x, lane = tid & 63, wave = tid >> 6;
    const int row = blockIdx.x * 4 + wave;
    const float* xp = tokens + (size_t)row * 1024 + lane * 16;
    float4 x[4];
#pragma unroll
    for (int q = 0; q < 4; ++q) x[q] = *(const float4*)&xp[q * 4];
    float ss = 0.f;
#pragma unroll
    for (int q = 0; q < 4; ++q)
        ss += x[q].x * x[q].x + x[q].y * x[q].y + x[q].z * x[q].z + x[q].w * x[q].w;
#pragma unroll
    for (int off = 32; off > 0; off >>= 1) ss += __shfl_down(ss, off);
    ss = __shfl(ss, 0);
    const float r = rsqrtf(ss * (1.0f / 1024.0f) + EPS);
    const float* wp = w_pre + lane * 16;
    short* op = tokbf + (size_t)row * 1024 + lane * 16;
#pragma unroll
    for (int h = 0; h < 2; ++h) {
        bf16x8 o;
#pragma unroll
        for (int q = 0; q < 2; ++q) {
            const float4 wv = *(const float4*)&wp[h * 8 + q * 4];
            const float4 xv = x[h * 2 + q];
            o[q * 4 + 0] = f2bf(xv.x * wv.x * r);
            o[q * 4 + 1] = f2bf(xv.y * wv.y * r);
            o[q * 4 + 2] = f2bf(xv.z * wv.z * r);
            o[q * 4 + 3] = f2bf(xv.w * wv.w * r);
        }
        *(bf16x8*)&op[h * 8] = o;
    }
}

// ---------------------------------------------------------------------------
// Kernel GT: token GEMM feats_pre = tokn @ W_down^T, bf16 MFMA 128x128 tiles.
// ---------------------------------------------------------------------------
__global__ __launch_bounds__(256) void k_gemm_tok(const short* __restrict__ tokbf,
                                                  const short* __restrict__ Wdbf,
                                                  float* __restrict__ feats) {
    __shared__ short As[128 * 32];
    __shared__ short Bs[128 * 32];
    const int tid = threadIdx.x, lane = tid & 63, w = tid >> 6;
    const int mt = blockIdx.x >> 2, nt = blockIdx.x & 3;
    const int wm = w >> 1, wn = w & 1;
    const short* hA = tokbf + (size_t)mt * 128 * 1024;
    const short* wB = Wdbf + (size_t)nt * 128 * 1024;

    f32x4 acc[4][4];
#pragma unroll
    for (int mi = 0; mi < 4; ++mi)
#pragma unroll
        for (int ni = 0; ni < 4; ++ni) acc[mi][ni] = (f32x4)0.f;

    const int rA = lane & 15, q8 = (lane >> 4) * 8;
    for (int kk = 0; kk < 1024; kk += 32) {
#pragma unroll
        for (int q = 0; q < 2; ++q) {
            const int cid = (w * 2 + q) * 64 + lane;
            const int r = cid >> 2, kc = cid & 3;
            const size_t go = (size_t)r * 1024 + kk + kc * 8;
            __builtin_amdgcn_global_load_lds(
                (const __attribute__((address_space(1))) uint32_t*)(hA + go),
                (__attribute__((address_space(3))) uint32_t*)&As[(w * 2 + q) * 512], 16, 0, 0);
            __builtin_amdgcn_global_load_lds(
                (const __attribute__((address_space(1))) uint32_t*)(wB + go),
                (__attribute__((address_space(3))) uint32_t*)&Bs[(w * 2 + q) * 512], 16, 0, 0);
        }
        __syncthreads();
        bf16x8 af[4], bfr[4];
#pragma unroll
        for (int mi = 0; mi < 4; ++mi)
            af[mi] = *(const bf16x8*)&As[(wm * 64 + mi * 16 + rA) * 32 + q8];
#pragma unroll
        for (int ni = 0; ni < 4; ++ni)
            bfr[ni] = *(const bf16x8*)&Bs[(wn * 64 + ni * 16 + rA) * 32 + q8];
#pragma unroll
        for (int mi = 0; mi < 4; ++mi)
#pragma unroll
            for (int ni = 0; ni < 4; ++ni)
                acc[mi][ni] = __builtin_amdgcn_mfma_f32_16x16x32_bf16(af[mi], bfr[ni], acc[mi][ni], 0, 0, 0);
        __syncthreads();
    }
    const int rowb = mt * 128 + wm * 64 + (lane >> 4) * 4;
    const int colb = nt * 128 + wn * 64 + (lane & 15);
#pragma unroll
    for (int mi = 0; mi < 4; ++mi)
#pragma unroll
        for (int ni = 0; ni < 4; ++ni)
#pragma unroll
            for (int rg = 0; rg < 4; ++rg)
                feats[(size_t)(rowb + mi * 16 + rg) * 512 + colb + ni * 16] = acc[mi][ni][rg];
}

// ---------------------------------------------------------------------------
// Kernel A3: one wave per token: rmsnorm(feats_pre, w_tok) -> silu -> W_proj.
// ---------------------------------------------------------------------------
__global__ __launch_bounds__(64) void k_params(
    const float* __restrict__ feats_pre, const float* __restrict__ w_tok,
    const float* __restrict__ W_proj, float* __restrict__ params) {
    const int tk = blockIdx.x;
    const int lane = threadIdx.x;
    const int d0 = lane * 8;
    const float* fp = feats_pre + (size_t)tk * 512 + d0;
    const float4 f0 = *(const float4*)&fp[0];
    const float4 f1 = *(const float4*)&fp[4];
    float ss = f0.x * f0.x + f0.y * f0.y + f0.z * f0.z + f0.w * f0.w
             + f1.x * f1.x + f1.y * f1.y + f1.z * f1.z + f1.w * f1.w;
#pragma unroll
    for (int off = 32; off > 0; off >>= 1) ss += __shfl_down(ss, off);
    ss = __shfl(ss, 0);
    const float rms = rsqrtf(ss * (1.0f / 512.0f) + EPS);

    const float4 wt0 = *(const float4*)&w_tok[d0];
    const float4 wt1 = *(const float4*)&w_tok[d0 + 4];
    float fv[8] = {f0.x, f0.y, f0.z, f0.w, f1.x, f1.y, f1.z, f1.w};
    float wv[8] = {wt0.x, wt0.y, wt0.z, wt0.w, wt1.x, wt1.y, wt1.z, wt1.w};
    float s[8];
#pragma unroll
    for (int j = 0; j < 8; ++j) {
        const float v = fv[j] * wv[j] * rms;
        s[j] = v / (1.0f + expf(-v));
    }
    float p[3];
#pragma unroll
    for (int q = 0; q < 3; ++q) {
        const float* Wp = W_proj + (size_t)q * 512 + d0;
        const float4 a = *(const float4*)&Wp[0];
        const float4 c = *(const float4*)&Wp[4];
        p[q] = s[0] * a.x + s[1] * a.y + s[2] * a.z + s[3] * a.w
             + s[4] * c.x + s[5] * c.y + s[6] * c.z + s[7] * c.w;
#pragma unroll
        for (int off = 32; off > 0; off >>= 1) p[q] += __shfl_down(p[q], off);
    }
    if (lane == 0) {
        float* po = params + (size_t)tk * 4;
        po[0] = 1.0f + p[0];
        po[1] = p[1];
        po[2] = 1.0f / (1.0f + expf(-p[2]));
    }
}

// ---------------------------------------------------------------------------
// Kernel CP: char prep. One wave per compact slot j: rmsnorm -> modulated silu
// -> bf16 h row; saves rms and gate per slot. Zeroes pad rows up to cnt
// rounded to 128 (GEMM tile).
// ---------------------------------------------------------------------------
__global__ __launch_bounds__(256) void k_prep(
    const float* __restrict__ chars, const float* __restrict__ w_char,
    const float* __restrict__ params, const int* __restrict__ v_list,
    const int* __restrict__ counts, short* __restrict__ hb,
    float* __restrict__ rms_l, float* __restrict__ g_l) {
    const int tid = threadIdx.x, lane = tid & 63, wave = tid >> 6;
    const int b = blockIdx.x >> 10;
    const int j = (blockIdx.x & 1023) * 4 + wave;
    const int cnt = counts[b];
    const int cpad = (cnt + 127) & ~127;
    if (j >= cpad) return;
    short* hrow = hb + ((size_t)(b << 12) + j) * 512 + lane * 8;
    if (j >= cnt) {
        *(bf16x8*)hrow = (bf16x8)0;
        return;
    }
    const int i = v_list[(b << 12) + j];
    const float* xp = chars + ((size_t)(b << 12) + i) * 512 + lane * 8;
    const float4 x0 = *(const float4*)&xp[0];
    const float4 x1 = *(const float4*)&xp[4];
    float ss = x0.x * x0.x + x0.y * x0.y + x0.z * x0.z + x0.w * x0.w
             + x1.x * x1.x + x1.y * x1.y + x1.z * x1.z + x1.w * x1.w;
#pragma unroll
    for (int off = 32; off > 0; off >>= 1) ss += __shfl_down(ss, off);
    ss = __shfl(ss, 0);
    const float rms = rsqrtf(ss * (1.0f / 512.0f) + EPS);
    const float* pp = params + (size_t)((b << 8) + (i >> 4)) * 4;
    const float s1 = pp[0], sh = pp[1], g = pp[2];
    const float4 w0 = *(const float4*)&w_char[lane * 8];
    const float4 w1 = *(const float4*)&w_char[lane * 8 + 4];
    float xv[8] = {x0.x, x0.y, x0.z, x0.w, x1.x, x1.y, x1.z, x1.w};
    float wv[8] = {w0.x, w0.y, w0.z, w0.w, w1.x, w1.y, w1.z, w1.w};
    bf16x8 o;
#pragma unroll
    for (int q = 0; q < 8; ++q) {
        const float cn = wv[q] * xv[q] * rms;
        const float a = cn * s1 + sh;
        o[q] = f2bf(a / (1.0f + expf(-a)));
    }
    *(bf16x8*)hrow = o;
    if (lane == 0) {
        rms_l[(b << 12) + j] = rms;
        g_l[(b << 12) + j] = g;
    }
}

// ---------------------------------------------------------------------------
// Kernel F: fill output rows j >= counts[b] with filler_embed.
// ---------------------------------------------------------------------------
__global__ __launch_bounds__(256) void k_fill(
    const float* __restrict__ filler, const int* __restrict__ counts,
    float* __restrict__ out) {
    const int gid = blockIdx.x * 256 + threadIdx.x;
    const size_t e4 = (size_t)gid * 4;
    const int slot = gid >> 7;
    const int b = slot >> 12;
    const int j = slot & 4095;
    if (j >= counts[b]) {
        const int e0 = (int)(e4 & 511);
        *(float4*)&out[e4] = *(const float4*)&filler[e0];
    }
}

// ---------------------------------------------------------------------------
// Kernel GF: fusion GEMM out[rows<cnt] = g*(h @ Wfus^T) + (1-g)*cn, bf16 MFMA
// 128x128 tiles over compacted rows; cn recomputed from gathered chars + rms.
// ---------------------------------------------------------------------------
__global__ __launch_bounds__(256) void k_gemm_fus(
    const short* __restrict__ hb, const short* __restrict__ Wbf,
    const float* __restrict__ chars, const float* __restrict__ w_char,
    const float* __restrict__ rms_l, const float* __restrict__ g_l,
    const int* __restrict__ v_list, const int* __restrict__ counts,
    float* __restrict__ out) {
    __shared__ short As[128 * 32];
    __shared__ short Bs[128 * 32];
    __shared__ float g_s[128], rms_s[128];
    __shared__ int idx_s[128];
    const int tid = threadIdx.x, lane = tid & 63, w = tid >> 6;
    const int b = blockIdx.x >> 7;
    const int mt = (blockIdx.x >> 2) & 31;
    const int nt = blockIdx.x & 3;
    const int cnt = counts[b];
    const int row0 = mt * 128;
    if (row0 >= cnt) return;
    const int wm = w >> 1, wn = w & 1;

    if (tid < 128) {
        const int j = row0 + tid;
        const bool valid = j < cnt;
        idx_s[tid] = valid ? v_list[(b << 12) + j] : 0;
        g_s[tid]   = valid ? g_l[(b << 12) + j] : 0.f;
        rms_s[tid] = valid ? rms_l[(b << 12) + j] : 0.f;
    }

    const short* hA = hb + ((size_t)(b << 12) + row0) * 512;
    const short* wB = Wbf + (size_t)nt * 128 * 512;

    f32x4 acc[4][4];
#pragma unroll
    for (int mi = 0; mi < 4; ++mi)
#pragma unroll
        for (int ni = 0; ni < 4; ++ni) acc[mi][ni] = (f32x4)0.f;

    const int rA = lane & 15, q8 = (lane >> 4) * 8;
    for (int kk = 0; kk < 512; kk += 32) {
#pragma unroll
        for (int q = 0; q < 2; ++q) {
            const int cid = (w * 2 + q) * 64 + lane;
            const int r = cid >> 2, kc = cid & 3;
            const size_t go = (size_t)r * 512 + kk + kc * 8;
            __builtin_amdgcn_global_load_lds(
                (const __attribute__((address_space(1))) uint32_t*)(hA + go),
                (__attribute__((address_space(3))) uint32_t*)&As[(w * 2 + q) * 512], 16, 0, 0);
            __builtin_amdgcn_global_load_lds(
                (const __attribute__((address_space(1))) uint32_t*)(wB + go),
                (__attribute__((address_space(3))) uint32_t*)&Bs[(w * 2 + q) * 512], 16, 0, 0);
        }
        __syncthreads();
        bf16x8 af[4], bfr[4];
#pragma unroll
        for (int mi = 0; mi < 4; ++mi)
            af[mi] = *(const bf16x8*)&As[(wm * 64 + mi * 16 + rA) * 32 + q8];
#pragma unroll
        for (int ni = 0; ni < 4; ++ni)
            bfr[ni] = *(const bf16x8*)&Bs[(wn * 64 + ni * 16 + rA) * 32 + q8];
#pragma unroll
        for (int mi = 0; mi < 4; ++mi)
#pragma unroll
            for (int ni = 0; ni < 4; ++ni)
                acc[mi][ni] = __builtin_amdgcn_mfma_f32_16x16x32_bf16(af[mi], bfr[ni], acc[mi][ni], 0, 0, 0);
        __syncthreads();
    }

    const int colb = nt * 128 + wn * 64 + (lane & 15);
    float wcv[4];
#pragma unroll
    for (int ni = 0; ni < 4; ++ni) wcv[ni] = w_char[colb + ni * 16];
#pragma unroll
    for (int mi = 0; mi < 4; ++mi) {
#pragma unroll
        for (int rg = 0; rg < 4; ++rg) {
            const int jl = wm * 64 + mi * 16 + (lane >> 4) * 4 + rg;
            const int j = row0 + jl;
            if (j < cnt) {
                const float g = g_s[jl], rm = rms_s[jl];
                const size_t xrow = ((size_t)(b << 12) + idx_s[jl]) * 512;
                const size_t orow = ((size_t)(b << 12) + j) * 512;
#pragma unroll
                for (int ni = 0; ni < 4; ++ni) {
                    const int col = colb + ni * 16;
                    const float x = chars[xrow + col];
                    const float cn = wcv[ni] * x * rm;
                    out[orow + col] = g * acc[mi][ni][rg] + (1.0f - g) * cn;
                }
            }
        }
    }
}

// ---------------------------------------------------------------------------
extern "C" void kernel_launch(void* const* d_in, const int* in_sizes, int n_in,
                              void* d_out, int out_size, void* d_ws, size_t ws_size,
                              hipStream_t stream) {
    const float* tokens = (const float*)d_in[0];
    const float* chars  = (const float*)d_in[2];
    const void*  cmask  = d_in[3];
    const float* filler = (const float*)d_in[4];
    const float* w_pre  = (const float*)d_in[5];
    const float* w_tok  = (const float*)d_in[6];
    const float* w_char = (const float*)d_in[7];
    const float* W_down = (const float*)d_in[8];
    const float* W_proj = (const float*)d_in[9];
    const float* W_fus  = (const float*)d_in[10];
    float* out = (float*)d_out;

    // workspace layout (~83 MB)
    float* feats_pre = (float*)d_ws;                          // 4096*512 f32 (8 MB)
    float* params    = feats_pre + (size_t)4096 * 512;        // 4096*4 f32
    int*   counts    = (int*)(params + (size_t)4096 * 4);     // 16
    int*   v_list    = counts + 16;                           // 65536
    float* rms_l     = (float*)(v_list + 65536);              // 65536
    float* g_l       = rms_l + 65536;                         // 65536
    short* Wbf       = (short*)(g_l + 65536);                 // 512*512 bf16
    short* hb        = Wbf + (size_t)512 * 512;               // 16*4096*512 bf16 (64 MB)
    short* tokbf     = hb + (size_t)16 * 4096 * 512;          // 4096*1024 bf16 (8 MB)
    short* Wdbf      = tokbf + (size_t)4096 * 1024;           // 512*1024 bf16 (1 MB)

    k_scan<<<16, 256, 0, stream>>>(cmask, v_list, counts);
    k_conv<<<256, 256, 0, stream>>>(W_fus, Wbf, 65536);       // 512*512/4
    k_conv<<<512, 256, 0, stream>>>(W_down, Wdbf, 131072);    // 512*1024/4
    k_tokprep<<<1024, 256, 0, stream>>>(tokens, w_pre, tokbf);
    k_gemm_tok<<<128, 256, 0, stream>>>(tokbf, Wdbf, feats_pre);
    k_params<<<4096, 64, 0, stream>>>(feats_pre, w_tok, W_proj, params);
    k_prep<<<16384, 256, 0, stream>>>(chars, w_char, params, v_list, counts, hb, rms_l, g_l);
    k_fill<<<32768, 256, 0, stream>>>(filler, counts, out);
    k_gemm_fus<<<2048, 256, 0, stream>>>(hb, Wbf, chars, w_char, rms_l, g_l, v_list, counts, out);
}